// Round 7
// baseline (58.120 us; speedup 1.0000x reference)
//
#include <hip/hip_runtime.h>

#define NDIM 64
#define NRANK 8
#define NK 16
#define CSTRIDE 641                 // floats per component: 1 + 64 + 512 + 64
#define ROWSTRIDE (CSTRIDE * NK)    // 10256 floats = 41024 B per row

// ---- DPP helpers --------------------------------------------------------

template <int CTRL>
__device__ __forceinline__ float dpp_mov(float x) {
  int t = __builtin_amdgcn_update_dpp(0, __builtin_bit_cast(int, x), CTRL,
                                      0xF, 0xF, true);
  return __builtin_bit_cast(float, t);
}

// sum across the 16-lane group (lane bits 0..3); all 16 lanes get the total
__device__ __forceinline__ void red16(float& x) {
  x += dpp_mov<0xB1>(x);   // quad_perm [1,0,3,2]  == xor 1
  x += dpp_mov<0x4E>(x);   // quad_perm [2,3,0,1]  == xor 2
  x += dpp_mov<0x141>(x);  // row_half_mirror      == xor 4
  x += dpp_mov<0x140>(x);  // row_mirror           == xor 8
}

// ---- kernel -------------------------------------------------------------
// One row per 256-thread block, 8192 independent blocks (block-level
// pipelining across resident blocks/CU). Wave w computes components
// k = 4w..4w+3; 16 lanes per component, dims d = de + 16*i per lane.
// All row data is loaded REGISTER-DIRECT (no LDS staging): per (lane,i) one
// 32 B W chunk (2x dwordx4, 512 B contiguous per 16-lane group) + mu + ld +
// label. 44 data VGPRs/lane = 11 KB in flight per wave, zero bank conflicts,
// exact traffic. LDS is only 32 floats of LSE scratch + one barrier.
// __launch_bounds__(256, 4): cap VGPR at 128 (live state ~105, fits) so 4
// blocks/CU stay resident — more cross-block overlap of tails/cold-starts.

__global__ __launch_bounds__(256, 4) void gmm_nll_kernel(
    const float* __restrict__ pred, const float* __restrict__ label,
    float* __restrict__ out, int nb) {
  __shared__ float scratch[32];
  const int tid = threadIdx.x;
  const int w = tid >> 6;       // wave id 0..3
  const int lane = tid & 63;
  const int kk = lane >> 4;     // component within wave
  const int de = lane & 15;     // dim-group within component
  const int b = blockIdx.x;

  const int k = 4 * w + kk;
  const float* comp = pred + (size_t)b * ROWSTRIDE + k * CSTRIDE;
  const float* lbl = label + (size_t)b * NDIM;

  // ---- register-direct loads of everything this lane needs ----
  float w_[4][8];   // W[d][0..7] for d = de + 16*i
  float mu_[4], ld_[4], lb_[4];
#pragma unroll
  for (int i = 0; i < 4; ++i) {
    const int d = de + 16 * i;
    __builtin_memcpy(&w_[i][0], comp + 1 + NDIM + 8 * d, 32);
    mu_[i] = comp[1 + d];
    ld_[i] = comp[1 + NDIM + NDIM * NRANK + d];  // log-diag
    lb_[i] = lbl[d];
  }
  float pi = comp[0];

  // ---- accumulate cap / b / mahal over this lane's 4 dims ----
  float capL[NRANK][NRANK];  // lower triangle (s <= r) used
  float bv[NRANK];
#pragma unroll
  for (int r = 0; r < NRANK; ++r) {
    bv[r] = 0.f;
#pragma unroll
    for (int s = 0; s <= r; ++s) capL[r][s] = 0.f;
  }
  float mahal1 = 0.f, ldsum = 0.f;

#pragma unroll
  for (int i = 0; i < 4; ++i) {
    float ldv = ld_[i];
    float sd = __expf(-0.5f * ldv);  // sqrt(1/d)
    float diff = lb_[i] - mu_[i];
    float u = diff * sd;
    mahal1 = fmaf(u, u, mahal1);
    ldsum += ldv;

    float v[NRANK];
#pragma unroll
    for (int r = 0; r < NRANK; ++r) v[r] = w_[i][r] * sd;
#pragma unroll
    for (int r = 0; r < NRANK; ++r) {
      bv[r] = fmaf(v[r], u, bv[r]);
#pragma unroll
      for (int s = 0; s <= r; ++s)
        capL[r][s] = fmaf(v[r], v[s], capL[r][s]);
    }
  }

  // reduce the 46 partials across the 16 de-lanes
  red16(mahal1);
  red16(ldsum);
#pragma unroll
  for (int r = 0; r < NRANK; ++r) {
    red16(bv[r]);
#pragma unroll
    for (int s = 0; s <= r; ++s) red16(capL[r][s]);
  }

  // cap = I + W^T D^-1 W
#pragma unroll
  for (int r = 0; r < NRANK; ++r) capL[r][r] += 1.0f;

  // in-place Cholesky (lower), fully unrolled; rsqrt + deferred single log
  float invd[NRANK];
  float prodinv = 1.0f;  // prod of 1/L_jj
#pragma unroll
  for (int j = 0; j < NRANK; ++j) {
    float s = capL[j][j];
#pragma unroll
    for (int p = 0; p < j; ++p) s = fmaf(-capL[j][p], capL[j][p], s);
    float inv = __frsqrt_rn(s);  // 1/L_jj
    invd[j] = inv;
    prodinv *= inv;
#pragma unroll
    for (int i2 = j + 1; i2 < NRANK; ++i2) {
      float t = capL[i2][j];
#pragma unroll
      for (int p = 0; p < j; ++p) t = fmaf(-capL[i2][p], capL[j][p], t);
      capL[i2][j] = t * inv;
    }
  }
  float logdetL = -__logf(prodinv);  // sum log(L_jj)

  // forward solve L y = b, accumulate |y|^2
  float y[NRANK];
  float ysq = 0.f;
#pragma unroll
  for (int i2 = 0; i2 < NRANK; ++i2) {
    float t = bv[i2];
#pragma unroll
    for (int j = 0; j < i2; ++j) t = fmaf(-capL[i2][j], y[j], t);
    y[i2] = t * invd[i2];
    ysq = fmaf(y[i2], y[i2], ysq);
  }

  float mahal = mahal1 - ysq;
  float logdet = 2.0f * logdetL + ldsum;
  const float c_dim_log2pi = 117.62413225019810f;  // 64 * log(2*pi)
  float comp_lp = -0.5f * (c_dim_log2pi + logdet + mahal);

  if (de == 0) {
    scratch[k] = pi;
    scratch[16 + k] = pi + comp_lp;
  }
  __syncthreads();

  // final logsumexp over the 16 components (wave 0, lanes 0..15)
  if (tid < 16) {
    float p = scratch[tid];
    float t2 = scratch[16 + tid];

    float m1 = p;
    m1 = fmaxf(m1, dpp_mov<0xB1>(m1));
    m1 = fmaxf(m1, dpp_mov<0x4E>(m1));
    m1 = fmaxf(m1, dpp_mov<0x141>(m1));
    m1 = fmaxf(m1, dpp_mov<0x140>(m1));
    float e1 = __expf(p - m1);
    red16(e1);

    float m2 = t2;
    m2 = fmaxf(m2, dpp_mov<0xB1>(m2));
    m2 = fmaxf(m2, dpp_mov<0x4E>(m2));
    m2 = fmaxf(m2, dpp_mov<0x141>(m2));
    m2 = fmaxf(m2, dpp_mov<0x140>(m2));
    float e2 = __expf(t2 - m2);
    red16(e2);

    if (tid == 0) out[b] = (m1 + __logf(e1)) - (m2 + __logf(e2));
  }
}

extern "C" void kernel_launch(void* const* d_in, const int* in_sizes, int n_in,
                              void* d_out, int out_size, void* d_ws,
                              size_t ws_size, hipStream_t stream) {
  const float* pred = (const float*)d_in[0];
  const float* label = (const float*)d_in[1];
  float* out = (float*)d_out;
  const int nb = out_size;  // 8192
  gmm_nll_kernel<<<dim3(nb), dim3(256), 0, stream>>>(pred, label, out, nb);
}